// Round 5
// baseline (243.577 us; speedup 1.0000x reference)
//
#include <hip/hip_runtime.h>
#include <math.h>

#define Bz 64
#define Sz 512
#define Hz 768
#define Nz 128
#define Ez 1024
#define GHz 128
#define FHz 256
#define Lz 2
#define BNz (Bz * Nz)          // 8192

typedef short bf16x8 __attribute__((ext_vector_type(8)));
typedef float f32x4  __attribute__((ext_vector_type(4)));
typedef unsigned short ushort;

__device__ inline ushort f2b(float f) {          // f32 -> bf16 bits, round-to-nearest-even
    union { float f; unsigned u; } v; v.f = f;
    return (ushort)((v.u + 0x7FFFu + ((v.u >> 16) & 1u)) >> 16);
}

// ============ k_stage: node gather (blocks 0..8191, 4 waves) + weight transpose (8192..8575)
//              + per-batch CSR build (8576..8639). LDS role-unioned in one arena.
__global__ __launch_bounds__(256) void k_stage(
        const float* __restrict__ lh, const int* __restrict__ submap,
        const float* __restrict__ wr, const float* __restrict__ br,
        const float* __restrict__ W1, const float* __restrict__ W2,
        const int* __restrict__ ei,
        ushort* __restrict__ nfb, ushort* __restrict__ W1T, ushort* __restrict__ W2T,
        int* __restrict__ rowptrG, int* __restrict__ srcsG,
        float* __restrict__ wnG, float* __restrict__ dinvG) {
    int blk = blockIdx.x, t = threadIdx.x;       // 256 threads
    __shared__ __align__(16) char arena[12288];

    if (blk >= 8192 && blk < 8576) {             // ---- weight conversion + transpose ----
        int i = (blk - 8192) * 256 + t;          // 0..98303 == Hz*GHz
        { int k = i >> 7, n = i & 127; W1T[n * Hz + k] = f2b(W1[i]); }
        if (i < GHz * GHz) { int k = i >> 7, n = i & 127; W2T[n * GHz + k] = f2b(W2[i]); }
        return;
    }
    if (blk >= 8576) {                           // ---- CSR build, 1 block per batch ----
        int b = blk - 8576;
        int*   srcl2 = (int*)arena;              // 4096
        int*   dstl2 = (int*)(arena + 4096);     // 4096
        int*   hist  = (int*)(arena + 8192);     // 512
        int*   off   = (int*)(arena + 8704);     // 512
        int*   rp    = (int*)(arena + 9216);     // 516
        float* di    = (float*)(arena + 9732);   // 512
        if (t < Nz) { hist[t] = 0; off[t] = 0; }
        __syncthreads();
        #pragma unroll
        for (int j = 0; j < 4; ++j) {
            int e = t + 256 * j;
            int s = ei[b * 2 * Ez + e], d = ei[b * 2 * Ez + Ez + e];
            srcl2[e] = s; dstl2[e] = d;
            atomicAdd(&hist[d], 1);
        }
        __syncthreads();
        if (t < Nz) {
            di[t] = rsqrtf((float)hist[t] + 1.0f);
            dinvG[b * Nz + t] = di[t];
        }
        __syncthreads();
        if (t < 64) {                            // wave shuffle-scan over 128 buckets
            int s0 = hist[2 * t], s1 = hist[2 * t + 1];
            int tot = s0 + s1, run = tot;
            #pragma unroll
            for (int o = 1; o < 64; o <<= 1) {
                int v = __shfl_up(run, o);
                if (t >= o) run += v;
            }
            int excl = run - tot;
            rp[2 * t] = excl; rp[2 * t + 1] = excl + s0;
            if (t == 63) rp[Nz] = run;
        }
        __syncthreads();
        #pragma unroll
        for (int j = 0; j < 4; ++j) {
            int e = t + 256 * j;
            int s = srcl2[e], d = dstl2[e];
            int pos = rp[d] + atomicAdd(&off[d], 1);
            srcsG[b * Ez + pos] = s;
            wnG[b * Ez + pos] = di[s] * di[d];
        }
        if (t < Nz) rowptrG[b * (Nz + 1) + t] = rp[t];
        if (t == 0) rowptrG[b * (Nz + 1) + Nz] = rp[Nz];
        return;
    }

    // ---- node gather: block = (b,n); 4 waves split rows; wave-synchronous gate ----
    int b = blk >> 7, n = blk & 127;
    int lane = t & 63, wid = t >> 6;             // 4 waves
    float* partial = (float*)arena;              // 3*768*4 = 9216 (waves 1..3)
    int*   list    = (int*)(arena + 9216);       // 2048
    int*   lcnt    = (int*)(arena + 11264);
    if (t == 0) *lcnt = 0;
    __syncthreads();
    #pragma unroll
    for (int j = 0; j < 2; ++j) {
        int s = t + 256 * j;
        if (submap[b * Sz + s] == n) { int p = atomicAdd(lcnt, 1); list[p] = s; }
    }
    __syncthreads();
    int cnt = *lcnt;
    float brv = br[0];
    const float* wp = wr + lane * 12;
    float4 w0 = *(const float4*)&wp[0];
    float4 w1 = *(const float4*)&wp[4];
    float4 w2 = *(const float4*)&wp[8];
    float4 a0 = {0,0,0,0}, a1 = {0,0,0,0}, a2 = {0,0,0,0};
    for (int i = wid; i < cnt; i += 4) {
        const float* x = lh + (size_t)(b * Sz + list[i]) * Hz + lane * 12;
        float4 v0 = *(const float4*)&x[0];
        float4 v1 = *(const float4*)&x[4];
        float4 v2 = *(const float4*)&x[8];
        float p = v0.x*w0.x + v0.y*w0.y + v0.z*w0.z + v0.w*w0.w
                + v1.x*w1.x + v1.y*w1.y + v1.z*w1.z + v1.w*w1.w
                + v2.x*w2.x + v2.y*w2.y + v2.z*w2.z + v2.w*w2.w;
        #pragma unroll
        for (int o = 32; o > 0; o >>= 1) p += __shfl_down(p, o);
        float z = __shfl(p, 0) + brv;
        float g = 1.0f / (1.0f + __expf(-z));
        a0.x += g*v0.x; a0.y += g*v0.y; a0.z += g*v0.z; a0.w += g*v0.w;
        a1.x += g*v1.x; a1.y += g*v1.y; a1.z += g*v1.z; a1.w += g*v1.w;
        a2.x += g*v2.x; a2.y += g*v2.y; a2.z += g*v2.z; a2.w += g*v2.w;
    }
    if (wid > 0) {
        float* pp = partial + (wid - 1) * Hz + lane * 12;
        *(float4*)&pp[0] = a0; *(float4*)&pp[4] = a1; *(float4*)&pp[8] = a2;
    }
    __syncthreads();
    if (wid == 0) {
        float invc = 1.0f / fmaxf((float)cnt, 1.0f);
        #pragma unroll
        for (int m = 0; m < 3; ++m) {
            const float* pp = partial + m * Hz + lane * 12;
            float4 p0 = *(const float4*)&pp[0];
            float4 p1 = *(const float4*)&pp[4];
            float4 p2 = *(const float4*)&pp[8];
            a0.x += p0.x; a0.y += p0.y; a0.z += p0.z; a0.w += p0.w;
            a1.x += p1.x; a1.y += p1.y; a1.z += p1.z; a1.w += p1.w;
            a2.x += p2.x; a2.y += p2.y; a2.z += p2.z; a2.w += p2.w;
        }
        float o[12];
        o[0]=a0.x*invc; o[1]=a0.y*invc; o[2]=a0.z*invc;  o[3]=a0.w*invc;
        o[4]=a1.x*invc; o[5]=a1.y*invc; o[6]=a1.z*invc;  o[7]=a1.w*invc;
        o[8]=a2.x*invc; o[9]=a2.y*invc; o[10]=a2.z*invc; o[11]=a2.w*invc;
        unsigned* ob = (unsigned*)(nfb + (size_t)(b * Nz + n) * Hz + lane * 12);
        #pragma unroll
        for (int j = 0; j < 6; ++j)
            ob[j] = (unsigned)f2b(o[2*j]) | ((unsigned)f2b(o[2*j+1]) << 16);
    }
}

// ============ fused per-batch GNN + HEAD, 1024 threads = 16 waves (4x4 wave grid) ============
// Round-4 lesson: the kernel was a lockstep barrier machine (28+ vmcnt-draining barriers).
// This version: GEMM1/GEMM2 run ENTIRELY from registers -- A (nfb) and B (W1T/W2T [n][k])
// hand each lane its MFMA fragment as one contiguous 16B global load, so there is NO LDS
// staging and NO barrier inside either GEMM. 6 barriers total in the whole kernel.
// MFMA layouts per m89/m91: A[m=lane&15][k=q*8+j]; B[k][n=lane&15]; C row=q*4+r, col=lane&15.
#define HP  132                 // hL row stride in f32 (scalar access only)
#define XP  136                 // x1 row stride in bf16 (272B = 17x16 -> ds_read_b128 aligned)
__global__ __launch_bounds__(1024) void k_gnn_fused(
        const ushort* __restrict__ nfb, const ushort* __restrict__ W1T,
        const ushort* __restrict__ W2T,
        const int* __restrict__ rowptrG, const int* __restrict__ srcsG,
        const float* __restrict__ wnG, const float* __restrict__ dinvG,
        const float* __restrict__ b1, const float* __restrict__ b2,
        const float* __restrict__ lh,
        const float* __restrict__ Wf1, const float* __restrict__ bf1,
        const float* __restrict__ Wf2, const float* __restrict__ bf2,
        float* __restrict__ outG) {
    __shared__ __align__(16) float  hL[128 * HP];    // 67.6KB  GEMM out (pre-aggregation)
    __shared__ __align__(16) ushort xb[128 * XP];    // 34.8KB  x1 bf16 [d][k]
    __shared__ __align__(16) float  inBuf[896 + 1024]; // 7.5KB inL(cls+pooled) | redA
    __shared__ __align__(16) float  wsumB[2048];     // 8KB    wsum | redB (time-shared)
    __shared__ float hvecL[256];
    __shared__ int   rp[Nz + 1];
    __shared__ int   srcl[Ez];
    __shared__ float wnl[Ez];
    __shared__ float dil[Nz];

    int b = blockIdx.x;
    int t = threadIdx.x;
    int w = t >> 6, lane = t & 63;
    int q = lane >> 4, l16 = lane & 15;
    int wm = w >> 2, wn2 = w & 3;                    // wave tile: rows wm*32+, cols wn2*32+
    int kq = q * 8;

    // ---- CSR -> LDS + cls -> inL (no dependency with GEMM1; covered by post-GEMM1 sync) ----
    if (t < Nz + 1) rp[t] = rowptrG[b * (Nz + 1) + t];
    if (t < Nz) dil[t] = dinvG[b * Nz + t];
    srcl[t] = srcsG[b * Ez + t];
    wnl[t]  = wnG[b * Ez + t];
    float* inL  = inBuf;                             // [896]
    float* redA = inBuf + 896;                       // [4][256] head partial (k 0..767)
    if (t < 224) ((float4*)inL)[t] = ((const float4*)(lh + (size_t)b * Sz * Hz))[t];

    // ---- GEMM1: hL = nf(128x768) @ W1(768x128); register-direct, barrier-free ----
    const ushort* A0 = nfb + (size_t)(b * Nz + wm * 32 + l16) * Hz;
    const ushort* A1 = A0 + 16 * Hz;
    const ushort* B0 = W1T + (size_t)(wn2 * 32 + l16) * Hz;
    const ushort* B1 = B0 + 16 * Hz;
    f32x4 acc00 = {0,0,0,0}, acc01 = {0,0,0,0}, acc10 = {0,0,0,0}, acc11 = {0,0,0,0};
    bf16x8 fa0 = *(const bf16x8*)&A0[kq], fa1 = *(const bf16x8*)&A1[kq];
    bf16x8 fb0 = *(const bf16x8*)&B0[kq], fb1 = *(const bf16x8*)&B1[kq];
    #pragma unroll 2
    for (int ks = 0; ks < Hz; ks += 64) {
        bf16x8 ga0 = *(const bf16x8*)&A0[ks + 32 + kq], ga1 = *(const bf16x8*)&A1[ks + 32 + kq];
        bf16x8 gb0 = *(const bf16x8*)&B0[ks + 32 + kq], gb1 = *(const bf16x8*)&B1[ks + 32 + kq];
        acc00 = __builtin_amdgcn_mfma_f32_16x16x32_bf16(fa0, fb0, acc00, 0, 0, 0);
        acc01 = __builtin_amdgcn_mfma_f32_16x16x32_bf16(fa0, fb1, acc01, 0, 0, 0);
        acc10 = __builtin_amdgcn_mfma_f32_16x16x32_bf16(fa1, fb0, acc10, 0, 0, 0);
        acc11 = __builtin_amdgcn_mfma_f32_16x16x32_bf16(fa1, fb1, acc11, 0, 0, 0);
        if (ks + 64 < Hz) {
            fa0 = *(const bf16x8*)&A0[ks + 64 + kq]; fa1 = *(const bf16x8*)&A1[ks + 64 + kq];
            fb0 = *(const bf16x8*)&B0[ks + 64 + kq]; fb1 = *(const bf16x8*)&B1[ks + 64 + kq];
        }
        acc00 = __builtin_amdgcn_mfma_f32_16x16x32_bf16(ga0, gb0, acc00, 0, 0, 0);
        acc01 = __builtin_amdgcn_mfma_f32_16x16x32_bf16(ga0, gb1, acc01, 0, 0, 0);
        acc10 = __builtin_amdgcn_mfma_f32_16x16x32_bf16(ga1, gb0, acc10, 0, 0, 0);
        acc11 = __builtin_amdgcn_mfma_f32_16x16x32_bf16(ga1, gb1, acc11, 0, 0, 0);
    }
    #pragma unroll
    for (int r = 0; r < 4; ++r) {
        hL[(wm * 32 +      q * 4 + r) * HP + wn2 * 32 +      l16] = acc00[r];
        hL[(wm * 32 +      q * 4 + r) * HP + wn2 * 32 + 16 + l16] = acc01[r];
        hL[(wm * 32 + 16 + q * 4 + r) * HP + wn2 * 32 +      l16] = acc10[r];
        hL[(wm * 32 + 16 + q * 4 + r) * HP + wn2 * 32 + 16 + l16] = acc11[r];
    }
    __syncthreads();                                 // hL + CSR + inL all visible

    // ---- edge1 (waves 0..7) || headA: cls @ Wf1[0:768] (waves 8..15) ----
    if (w < 8) {
        float b1v0 = b1[lane], b1v1 = b1[lane + 64];
        for (int d = w; d < Nz; d += 8) {
            float dd = dil[d];
            float a0 = hL[d * HP + lane] * dd * dd;
            float a1 = hL[d * HP + lane + 64] * dd * dd;
            float c0 = 0.f, c1 = 0.f;
            int i = rp[d], pe = rp[d + 1];
            for (; i + 4 <= pe; i += 4) {
                int s0_ = srcl[i], s1_ = srcl[i+1], s2_ = srcl[i+2], s3_ = srcl[i+3];
                float n0 = wnl[i], n1 = wnl[i+1], n2 = wnl[i+2], n3 = wnl[i+3];
                float h0a = hL[s0_*HP+lane], h0b = hL[s0_*HP+lane+64];
                float h1a = hL[s1_*HP+lane], h1b = hL[s1_*HP+lane+64];
                float h2a = hL[s2_*HP+lane], h2b = hL[s2_*HP+lane+64];
                float h3a = hL[s3_*HP+lane], h3b = hL[s3_*HP+lane+64];
                a0 += h0a*n0; a1 += h0b*n0; c0 += h1a*n1; c1 += h1b*n1;
                a0 += h2a*n2; a1 += h2b*n2; c0 += h3a*n3; c1 += h3b*n3;
            }
            for (; i < pe; ++i) {
                int s_ = srcl[i]; float nm = wnl[i];
                a0 += hL[s_*HP+lane]*nm; a1 += hL[s_*HP+lane+64]*nm;
            }
            a0 += c0; a1 += c1;
            xb[d * XP + lane]      = f2b(fmaxf(a0 + b1v0, 0.0f));
            xb[d * XP + lane + 64] = f2b(fmaxf(a1 + b1v1, 0.0f));
        }
    } else {
        int tt = t - 512;
        int f2 = tt & 127, kkq = tt >> 7;            // 4-way k split, 192 each
        const float* Wp = Wf1 + (size_t)(kkq * 192) * FHz + f2 * 2;
        const float* ip = inL + kkq * 192;
        float ax = 0.f, ay = 0.f;
        #pragma unroll 8
        for (int k = 0; k < 192; ++k) {
            float iv = ip[k];
            float2 wv = *(const float2*)&Wp[(size_t)k * FHz];
            ax += iv * wv.x; ay += iv * wv.y;
        }
        redA[kkq * 256 + f2 * 2]     = ax;
        redA[kkq * 256 + f2 * 2 + 1] = ay;
    }
    __syncthreads();

    // ---- GEMM2: hL = x1(128x128, LDS) @ W2(128x128); A from xb, B register-direct ----
    const ushort* C0 = W2T + (size_t)(wn2 * 32 + l16) * GHz;
    const ushort* C1 = C0 + 16 * GHz;
    acc00 = (f32x4){0,0,0,0}; acc01 = (f32x4){0,0,0,0};
    acc10 = (f32x4){0,0,0,0}; acc11 = (f32x4){0,0,0,0};
    #pragma unroll
    for (int ks = 0; ks < GHz; ks += 32) {
        bf16x8 xa0 = *(const bf16x8*)&xb[(wm * 32 +      l16) * XP + ks + kq];
        bf16x8 xa1 = *(const bf16x8*)&xb[(wm * 32 + 16 + l16) * XP + ks + kq];
        bf16x8 wb0 = *(const bf16x8*)&C0[ks + kq];
        bf16x8 wb1 = *(const bf16x8*)&C1[ks + kq];
        acc00 = __builtin_amdgcn_mfma_f32_16x16x32_bf16(xa0, wb0, acc00, 0, 0, 0);
        acc01 = __builtin_amdgcn_mfma_f32_16x16x32_bf16(xa0, wb1, acc01, 0, 0, 0);
        acc10 = __builtin_amdgcn_mfma_f32_16x16x32_bf16(xa1, wb0, acc10, 0, 0, 0);
        acc11 = __builtin_amdgcn_mfma_f32_16x16x32_bf16(xa1, wb1, acc11, 0, 0, 0);
    }
    __syncthreads();                                 // all edge1 hL reads done before rewrite
    #pragma unroll
    for (int r = 0; r < 4; ++r) {
        hL[(wm * 32 +      q * 4 + r) * HP + wn2 * 32 +      l16] = acc00[r];
        hL[(wm * 32 +      q * 4 + r) * HP + wn2 * 32 + 16 + l16] = acc01[r];
        hL[(wm * 32 + 16 + q * 4 + r) * HP + wn2 * 32 +      l16] = acc10[r];
        hL[(wm * 32 + 16 + q * 4 + r) * HP + wn2 * 32 + 16 + l16] = acc11[r];
    }
    __syncthreads();

    // ---- edge2 + mean-pool (all 16 waves, 8 d's each; x2 never materialized) ----
    float b2v0 = b2[lane], b2v1 = b2[lane + 64];
    float p0 = 0.0f, p1 = 0.0f;
    for (int d = w; d < Nz; d += 16) {
        float dd = dil[d];
        float a0 = hL[d * HP + lane] * dd * dd;
        float a1 = hL[d * HP + lane + 64] * dd * dd;
        float c0 = 0.f, c1 = 0.f;
        int i = rp[d], pe = rp[d + 1];
        for (; i + 4 <= pe; i += 4) {
            int s0_ = srcl[i], s1_ = srcl[i+1], s2_ = srcl[i+2], s3_ = srcl[i+3];
            float n0 = wnl[i], n1 = wnl[i+1], n2 = wnl[i+2], n3 = wnl[i+3];
            float h0a = hL[s0_*HP+lane], h0b = hL[s0_*HP+lane+64];
            float h1a = hL[s1_*HP+lane], h1b = hL[s1_*HP+lane+64];
            float h2a = hL[s2_*HP+lane], h2b = hL[s2_*HP+lane+64];
            float h3a = hL[s3_*HP+lane], h3b = hL[s3_*HP+lane+64];
            a0 += h0a*n0; a1 += h0b*n0; c0 += h1a*n1; c1 += h1b*n1;
            a0 += h2a*n2; a1 += h2b*n2; c0 += h3a*n3; c1 += h3b*n3;
        }
        for (; i < pe; ++i) {
            int s_ = srcl[i]; float nm = wnl[i];
            a0 += hL[s_*HP+lane]*nm; a1 += hL[s_*HP+lane+64]*nm;
        }
        a0 += c0; a1 += c1;
        p0 += fmaxf(a0 + b2v0, 0.0f);
        p1 += fmaxf(a1 + b2v1, 0.0f);
    }
    wsumB[w * 128 + lane]      = p0;
    wsumB[w * 128 + lane + 64] = p1;
    __syncthreads();
    if (t < Nz) {
        float s = 0.0f;
        #pragma unroll
        for (int ww = 0; ww < 16; ++ww) s += wsumB[ww * 128 + t];
        inL[Hz + t] = s * (1.0f / Nz);               // pooled -> head input
    }
    __syncthreads();

    // ---- headB: pooled @ Wf1[768:896] (all threads, 16 k each; redB aliases wsumB) ----
    float* redB = wsumB;                             // [8][256]
    {
        int f2 = t & 127, kc8 = t >> 7;
        const float* Wp = Wf1 + (size_t)(Hz + kc8 * 16) * FHz + f2 * 2;
        const float* ip = inL + Hz + kc8 * 16;
        float ax = 0.f, ay = 0.f;
        #pragma unroll
        for (int k = 0; k < 16; ++k) {
            float iv = ip[k];
            float2 wv = *(const float2*)&Wp[(size_t)k * FHz];
            ax += iv * wv.x; ay += iv * wv.y;
        }
        redB[kc8 * 256 + f2 * 2]     = ax;
        redB[kc8 * 256 + f2 * 2 + 1] = ay;
    }
    __syncthreads();
    if (t < 128) {
        float sx = bf1[2 * t], sy = bf1[2 * t + 1];
        #pragma unroll
        for (int m = 0; m < 4; ++m) { sx += redA[m * 256 + 2 * t]; sy += redA[m * 256 + 2 * t + 1]; }
        #pragma unroll
        for (int m = 0; m < 8; ++m) { sx += redB[m * 256 + 2 * t]; sy += redB[m * 256 + 2 * t + 1]; }
        hvecL[2 * t]     = fmaxf(sx, 0.0f);
        hvecL[2 * t + 1] = fmaxf(sy, 0.0f);
    }
    __syncthreads();
    if (t < 128) {
        int l = t >> 6, j0 = t & 63;
        float s = 0.0f;
        #pragma unroll
        for (int m = 0; m < 4; ++m) s += hvecL[j0 + 64 * m] * Wf2[(j0 + 64 * m) * Lz + l];
        #pragma unroll
        for (int o = 32; o > 0; o >>= 1) s += __shfl_down(s, o);
        if (j0 == 0) outG[b * Lz + l] = s + bf2[l];
    }
}

extern "C" void kernel_launch(void* const* d_in, const int* in_sizes, int n_in,
                              void* d_out, int out_size, void* d_ws, size_t ws_size,
                              hipStream_t stream) {
    const float* lh     = (const float*)d_in[0];
    const int*   submap = (const int*)d_in[1];
    const int*   ei     = (const int*)d_in[2];
    const float* wr  = (const float*)d_in[4];
    const float* br  = (const float*)d_in[5];
    const float* W1  = (const float*)d_in[6];
    const float* b1  = (const float*)d_in[7];
    const float* W2  = (const float*)d_in[8];
    const float* b2  = (const float*)d_in[9];
    const float* Wf1 = (const float*)d_in[10];
    const float* bf1 = (const float*)d_in[11];
    const float* Wf2 = (const float*)d_in[12];
    const float* bf2 = (const float*)d_in[13];
    float* out = (float*)d_out;

    // ---- workspace layout (16B-aligned chunks) ----
    char* p = (char*)d_ws;
    ushort* nfb  = (ushort*)p;  p += (size_t)BNz * Hz * 2;      // 12.6 MB bf16
    ushort* W1T  = (ushort*)p;  p += (size_t)Hz * GHz * 2;      // transposed [n][k]
    ushort* W2T  = (ushort*)p;  p += (size_t)GHz * GHz * 2;     // transposed [n][k]
    int*    rowptrG = (int*)p;  p += (size_t)Bz * (Nz + 1) * 4;
    int*    srcsG   = (int*)p;  p += (size_t)Bz * Ez * 4;
    float*  wnG     = (float*)p; p += (size_t)Bz * Ez * 4;
    float*  dinvG   = (float*)p; p += (size_t)Bz * Nz * 4;

    // 2 dispatches; no memsets, no global atomics; GNN+head intermediates never leave LDS
    k_stage<<<8192 + 384 + 64, 256, 0, stream>>>(lh, submap, wr, br, W1, W2, ei,
                                                 nfb, W1T, W2T, rowptrG, srcsG, wnG, dinvG);
    k_gnn_fused<<<Bz, 1024, 0, stream>>>(nfb, W1T, W2T, rowptrG, srcsG, wnG, dinvG,
                                         b1, b2, lh, Wf1, bf1, Wf2, bf2, out);
}

// Round 6
// 207.458 us; speedup vs baseline: 1.1741x; 1.1741x over previous
//
#include <hip/hip_runtime.h>
#include <math.h>

#define Bz 64
#define Sz 512
#define Hz 768
#define Nz 128
#define Ez 1024
#define GHz 128
#define FHz 256
#define Lz 2
#define BNz (Bz * Nz)          // 8192

typedef short bf16x8 __attribute__((ext_vector_type(8)));
typedef float f32x4  __attribute__((ext_vector_type(4)));
typedef unsigned short ushort;

__device__ inline ushort f2b(float f) {          // f32 -> bf16 bits, round-to-nearest-even
    union { float f; unsigned u; } v; v.f = f;
    return (ushort)((v.u + 0x7FFFu + ((v.u >> 16) & 1u)) >> 16);
}

// ============ k_stage: node gather (blocks 0..8191, 4 waves) + weight transpose (8192..8575)
//              + per-batch CSR build (8576..8639). LDS role-unioned in one arena.
__global__ __launch_bounds__(256) void k_stage(
        const float* __restrict__ lh, const int* __restrict__ submap,
        const float* __restrict__ wr, const float* __restrict__ br,
        const float* __restrict__ W1, const float* __restrict__ W2,
        const int* __restrict__ ei,
        ushort* __restrict__ nfb, ushort* __restrict__ W1T, ushort* __restrict__ W2T,
        int* __restrict__ rowptrG, int* __restrict__ srcsG,
        float* __restrict__ wnG, float* __restrict__ dinvG) {
    int blk = blockIdx.x, t = threadIdx.x;       // 256 threads
    __shared__ __align__(16) char arena[12288];

    if (blk >= 8192 && blk < 8576) {             // ---- weight conversion + transpose ----
        int i = (blk - 8192) * 256 + t;          // 0..98303 == Hz*GHz
        { int k = i >> 7, n = i & 127; W1T[n * Hz + k] = f2b(W1[i]); }
        if (i < GHz * GHz) { int k = i >> 7, n = i & 127; W2T[n * GHz + k] = f2b(W2[i]); }
        return;
    }
    if (blk >= 8576) {                           // ---- CSR build, 1 block per batch ----
        int b = blk - 8576;
        int*   srcl2 = (int*)arena;              // 4096
        int*   dstl2 = (int*)(arena + 4096);     // 4096
        int*   hist  = (int*)(arena + 8192);     // 512
        int*   off   = (int*)(arena + 8704);     // 512
        int*   rp    = (int*)(arena + 9216);     // 516
        float* di    = (float*)(arena + 9732);   // 512
        if (t < Nz) { hist[t] = 0; off[t] = 0; }
        __syncthreads();
        #pragma unroll
        for (int j = 0; j < 4; ++j) {
            int e = t + 256 * j;
            int s = ei[b * 2 * Ez + e], d = ei[b * 2 * Ez + Ez + e];
            srcl2[e] = s; dstl2[e] = d;
            atomicAdd(&hist[d], 1);
        }
        __syncthreads();
        if (t < Nz) {
            di[t] = rsqrtf((float)hist[t] + 1.0f);
            dinvG[b * Nz + t] = di[t];
        }
        __syncthreads();
        if (t < 64) {                            // wave shuffle-scan over 128 buckets
            int s0 = hist[2 * t], s1 = hist[2 * t + 1];
            int tot = s0 + s1, run = tot;
            #pragma unroll
            for (int o = 1; o < 64; o <<= 1) {
                int v = __shfl_up(run, o);
                if (t >= o) run += v;
            }
            int excl = run - tot;
            rp[2 * t] = excl; rp[2 * t + 1] = excl + s0;
            if (t == 63) rp[Nz] = run;
        }
        __syncthreads();
        #pragma unroll
        for (int j = 0; j < 4; ++j) {
            int e = t + 256 * j;
            int s = srcl2[e], d = dstl2[e];
            int pos = rp[d] + atomicAdd(&off[d], 1);
            srcsG[b * Ez + pos] = s;
            wnG[b * Ez + pos] = di[s] * di[d];
        }
        if (t < Nz) rowptrG[b * (Nz + 1) + t] = rp[t];
        if (t == 0) rowptrG[b * (Nz + 1) + Nz] = rp[Nz];
        return;
    }

    // ---- node gather: block = (b,n); 4 waves split rows; wave-synchronous gate ----
    int b = blk >> 7, n = blk & 127;
    int lane = t & 63, wid = t >> 6;             // 4 waves
    float* partial = (float*)arena;              // 3*768*4 = 9216 (waves 1..3)
    int*   list    = (int*)(arena + 9216);       // 2048
    int*   lcnt    = (int*)(arena + 11264);
    if (t == 0) *lcnt = 0;
    __syncthreads();
    #pragma unroll
    for (int j = 0; j < 2; ++j) {
        int s = t + 256 * j;
        if (submap[b * Sz + s] == n) { int p = atomicAdd(lcnt, 1); list[p] = s; }
    }
    __syncthreads();
    int cnt = *lcnt;
    float brv = br[0];
    const float* wp = wr + lane * 12;
    float4 w0 = *(const float4*)&wp[0];
    float4 w1 = *(const float4*)&wp[4];
    float4 w2 = *(const float4*)&wp[8];
    float4 a0 = {0,0,0,0}, a1 = {0,0,0,0}, a2 = {0,0,0,0};
    for (int i = wid; i < cnt; i += 4) {
        const float* x = lh + (size_t)(b * Sz + list[i]) * Hz + lane * 12;
        float4 v0 = *(const float4*)&x[0];
        float4 v1 = *(const float4*)&x[4];
        float4 v2 = *(const float4*)&x[8];
        float p = v0.x*w0.x + v0.y*w0.y + v0.z*w0.z + v0.w*w0.w
                + v1.x*w1.x + v1.y*w1.y + v1.z*w1.z + v1.w*w1.w
                + v2.x*w2.x + v2.y*w2.y + v2.z*w2.z + v2.w*w2.w;
        #pragma unroll
        for (int o = 32; o > 0; o >>= 1) p += __shfl_down(p, o);
        float z = __shfl(p, 0) + brv;
        float g = 1.0f / (1.0f + __expf(-z));
        a0.x += g*v0.x; a0.y += g*v0.y; a0.z += g*v0.z; a0.w += g*v0.w;
        a1.x += g*v1.x; a1.y += g*v1.y; a1.z += g*v1.z; a1.w += g*v1.w;
        a2.x += g*v2.x; a2.y += g*v2.y; a2.z += g*v2.z; a2.w += g*v2.w;
    }
    if (wid > 0) {
        float* pp = partial + (wid - 1) * Hz + lane * 12;
        *(float4*)&pp[0] = a0; *(float4*)&pp[4] = a1; *(float4*)&pp[8] = a2;
    }
    __syncthreads();
    if (wid == 0) {
        float invc = 1.0f / fmaxf((float)cnt, 1.0f);
        #pragma unroll
        for (int m = 0; m < 3; ++m) {
            const float* pp = partial + m * Hz + lane * 12;
            float4 p0 = *(const float4*)&pp[0];
            float4 p1 = *(const float4*)&pp[4];
            float4 p2 = *(const float4*)&pp[8];
            a0.x += p0.x; a0.y += p0.y; a0.z += p0.z; a0.w += p0.w;
            a1.x += p1.x; a1.y += p1.y; a1.z += p1.z; a1.w += p1.w;
            a2.x += p2.x; a2.y += p2.y; a2.z += p2.z; a2.w += p2.w;
        }
        float o[12];
        o[0]=a0.x*invc; o[1]=a0.y*invc; o[2]=a0.z*invc;  o[3]=a0.w*invc;
        o[4]=a1.x*invc; o[5]=a1.y*invc; o[6]=a1.z*invc;  o[7]=a1.w*invc;
        o[8]=a2.x*invc; o[9]=a2.y*invc; o[10]=a2.z*invc; o[11]=a2.w*invc;
        unsigned* ob = (unsigned*)(nfb + (size_t)(b * Nz + n) * Hz + lane * 12);
        #pragma unroll
        for (int j = 0; j < 6; ++j)
            ob[j] = (unsigned)f2b(o[2*j]) | ((unsigned)f2b(o[2*j+1]) << 16);
    }
}

// ============ fused per-batch GNN + HEAD, 1024 threads = 16 waves (4x4 wave grid) ============
// ROUND-4 VERSION (best measured: 214us total). Round-5's register-direct GEMM regressed
// (VGPR 52 -> compiler collapsed the prefetch pipeline into serial cache-cold loads, 77us).
// LDS-staged GEMMs with reg-prefetch; edge1 || headA wave split; head fully fused.
// LDS strides: ds_read_b128 needs 16B-aligned rows: GSP=72 (144B), XP=136 (272B).
#define GSP 72                  // staging row stride in bf16
#define HP  132                 // h row stride in f32 (scalar access only)
#define XP  136                 // x1 row stride in bf16
__global__ __launch_bounds__(1024) void k_gnn_fused(
        const ushort* __restrict__ nfb, const ushort* __restrict__ W1T,
        const ushort* __restrict__ W2T,
        const int* __restrict__ rowptrG, const int* __restrict__ srcsG,
        const float* __restrict__ wnG, const float* __restrict__ dinvG,
        const float* __restrict__ b1, const float* __restrict__ b2,
        const float* __restrict__ lh,
        const float* __restrict__ Wf1, const float* __restrict__ bf1,
        const float* __restrict__ Wf2, const float* __restrict__ bf2,
        float* __restrict__ outG) {
    __shared__ __align__(16) ushort As[128 * GSP];   // 18.4KB; reused: head in[896]+redA[1024]
    __shared__ __align__(16) ushort Bs[128 * GSP];   // 18.4KB; reused: redB[2048]+hvec[256]
    __shared__ __align__(16) float  hL[128 * HP];    // 67.6KB  GEMM out (pre-aggregation)
    __shared__ __align__(16) ushort xb[128 * XP];    // 34.8KB  x1 bf16 [d][k]
    __shared__ int   rp[Nz + 1];
    __shared__ int   srcl[Ez];
    __shared__ float wnl[Ez];
    __shared__ float dil[Nz];
    __shared__ float wsum[16 * 128];                 // 8KB

    int b = blockIdx.x;
    int t = threadIdx.x;
    int w = t >> 6, lane = t & 63;
    int q = lane >> 4, l16 = lane & 15;
    int wm = w >> 2, wn2 = w & 3;                    // wave tile: rows wm*32+, cols wn2*32+

    // ---- CSR -> LDS (1 elem/thread) ----
    if (t < Nz + 1) rp[t] = rowptrG[b * (Nz + 1) + t];
    if (t < Nz) dil[t] = dinvG[b * Nz + t];
    srcl[t] = srcsG[b * Ez + t];
    wnl[t]  = wnG[b * Ez + t];

    // staging: 1024 uint4 chunks each for A and B (128 rows x 8 segs), 1 per thread
    int ar = t >> 3, as_ = t & 7;

    f32x4 acc[2][2];
    #pragma unroll
    for (int mf = 0; mf < 2; ++mf)
        #pragma unroll
        for (int nf = 0; nf < 2; ++nf) acc[mf][nf] = (f32x4){0, 0, 0, 0};

    // ---- GEMM1: hL = nf(128x768) @ W1(768x128), reg-prefetched 64-k steps ----
    const ushort* Ab = nfb + (size_t)b * Nz * Hz;
    uint4 apre, bpre;
    auto loadT1 = [&](int k0) {
        apre = *(const uint4*)&Ab[(size_t)ar * Hz + k0 + as_ * 8];
        bpre = *(const uint4*)&W1T[(size_t)ar * Hz + k0 + as_ * 8];
    };
    loadT1(0);
    for (int k0 = 0; k0 < Hz; k0 += 64) {
        __syncthreads();
        *(uint4*)&As[ar * GSP + as_ * 8] = apre;
        *(uint4*)&Bs[ar * GSP + as_ * 8] = bpre;
        if (k0 + 64 < Hz) loadT1(k0 + 64);
        __syncthreads();
        #pragma unroll
        for (int ks = 0; ks < 64; ks += 32)
            #pragma unroll
            for (int mf = 0; mf < 2; ++mf) {
                bf16x8 af = *(const bf16x8*)&As[(wm * 32 + mf * 16 + l16) * GSP + ks + q * 8];
                #pragma unroll
                for (int nf = 0; nf < 2; ++nf) {
                    bf16x8 bv = *(const bf16x8*)&Bs[(wn2 * 32 + nf * 16 + l16) * GSP + ks + q * 8];
                    acc[mf][nf] = __builtin_amdgcn_mfma_f32_16x16x32_bf16(af, bv, acc[mf][nf], 0, 0, 0);
                }
            }
    }
    #pragma unroll
    for (int mf = 0; mf < 2; ++mf)
        #pragma unroll
        for (int nf = 0; nf < 2; ++nf)
            #pragma unroll
            for (int r = 0; r < 4; ++r)
                hL[(wm * 32 + mf * 16 + q * 4 + r) * HP + wn2 * 32 + nf * 16 + l16] = acc[mf][nf][r];
    __syncthreads();                                 // As free; hL complete

    // ---- cls -> inL (As region) ----
    float* inL  = (float*)As;                        // [896]
    float* redA = inL + 896;                         // [4][256] head partial (k 0..767)
    if (t < 224) ((float4*)inL)[t] = ((const float4*)(lh + (size_t)b * Sz * Hz))[t];
    __syncthreads();                                 // inL visible to headA waves

    // ---- edge1 (waves 0..7) || headA: cls @ Wf1[0:768] (waves 8..15) ----
    if (w < 8) {
        float b1v0 = b1[lane], b1v1 = b1[lane + 64];
        for (int d = w; d < Nz; d += 8) {
            float dd = dil[d];
            float a0 = hL[d * HP + lane] * dd * dd;
            float a1 = hL[d * HP + lane + 64] * dd * dd;
            float c0 = 0.f, c1 = 0.f;
            int i = rp[d], pe = rp[d + 1];
            for (; i + 4 <= pe; i += 4) {
                int s0_ = srcl[i], s1_ = srcl[i+1], s2_ = srcl[i+2], s3_ = srcl[i+3];
                float n0 = wnl[i], n1 = wnl[i+1], n2 = wnl[i+2], n3 = wnl[i+3];
                float h0a = hL[s0_*HP+lane], h0b = hL[s0_*HP+lane+64];
                float h1a = hL[s1_*HP+lane], h1b = hL[s1_*HP+lane+64];
                float h2a = hL[s2_*HP+lane], h2b = hL[s2_*HP+lane+64];
                float h3a = hL[s3_*HP+lane], h3b = hL[s3_*HP+lane+64];
                a0 += h0a*n0; a1 += h0b*n0; c0 += h1a*n1; c1 += h1b*n1;
                a0 += h2a*n2; a1 += h2b*n2; c0 += h3a*n3; c1 += h3b*n3;
            }
            for (; i < pe; ++i) {
                int s_ = srcl[i]; float nm = wnl[i];
                a0 += hL[s_*HP+lane]*nm; a1 += hL[s_*HP+lane+64]*nm;
            }
            a0 += c0; a1 += c1;
            xb[d * XP + lane]      = f2b(fmaxf(a0 + b1v0, 0.0f));
            xb[d * XP + lane + 64] = f2b(fmaxf(a1 + b1v1, 0.0f));
        }
    } else {
        int tt = t - 512;
        int f2 = tt & 127, kq = tt >> 7;             // 4-way k split, 192 each
        const float* Wp = Wf1 + (size_t)(kq * 192) * FHz + f2 * 2;
        const float* ip = inL + kq * 192;
        float ax = 0.f, ay = 0.f;
        #pragma unroll 8
        for (int k = 0; k < 192; ++k) {
            float iv = ip[k];
            float2 wv = *(const float2*)&Wp[(size_t)k * FHz];
            ax += iv * wv.x; ay += iv * wv.y;
        }
        redA[kq * 256 + f2 * 2]     = ax;
        redA[kq * 256 + f2 * 2 + 1] = ay;
    }
    __syncthreads();

    // ---- GEMM2: hL = x1(128x128, LDS) @ W2(128x128) ----
    #pragma unroll
    for (int mf = 0; mf < 2; ++mf)
        #pragma unroll
        for (int nf = 0; nf < 2; ++nf) acc[mf][nf] = (f32x4){0, 0, 0, 0};
    for (int k0 = 0; k0 < GHz; k0 += 64) {
        __syncthreads();
        *(uint4*)&Bs[ar * GSP + as_ * 8] = *(const uint4*)&W2T[(size_t)ar * GHz + k0 + as_ * 8];
        __syncthreads();
        #pragma unroll
        for (int ks = 0; ks < 64; ks += 32)
            #pragma unroll
            for (int mf = 0; mf < 2; ++mf) {
                bf16x8 af = *(const bf16x8*)&xb[(wm * 32 + mf * 16 + l16) * XP + k0 + ks + q * 8];
                #pragma unroll
                for (int nf = 0; nf < 2; ++nf) {
                    bf16x8 bv = *(const bf16x8*)&Bs[(wn2 * 32 + nf * 16 + l16) * GSP + ks + q * 8];
                    acc[mf][nf] = __builtin_amdgcn_mfma_f32_16x16x32_bf16(af, bv, acc[mf][nf], 0, 0, 0);
                }
            }
    }
    __syncthreads();                                 // xb/Bs readers done before hL rewrite is seen
    #pragma unroll
    for (int mf = 0; mf < 2; ++mf)
        #pragma unroll
        for (int nf = 0; nf < 2; ++nf)
            #pragma unroll
            for (int r = 0; r < 4; ++r)
                hL[(wm * 32 + mf * 16 + q * 4 + r) * HP + wn2 * 32 + nf * 16 + l16] = acc[mf][nf][r];
    __syncthreads();

    // ---- edge2 + mean-pool (all 16 waves, 8 d's each) ----
    float b2v0 = b2[lane], b2v1 = b2[lane + 64];
    float p0 = 0.0f, p1 = 0.0f;
    for (int d = w; d < Nz; d += 16) {
        float dd = dil[d];
        float a0 = hL[d * HP + lane] * dd * dd;
        float a1 = hL[d * HP + lane + 64] * dd * dd;
        float c0 = 0.f, c1 = 0.f;
        int i = rp[d], pe = rp[d + 1];
        for (; i + 4 <= pe; i += 4) {
            int s0_ = srcl[i], s1_ = srcl[i+1], s2_ = srcl[i+2], s3_ = srcl[i+3];
            float n0 = wnl[i], n1 = wnl[i+1], n2 = wnl[i+2], n3 = wnl[i+3];
            float h0a = hL[s0_*HP+lane], h0b = hL[s0_*HP+lane+64];
            float h1a = hL[s1_*HP+lane], h1b = hL[s1_*HP+lane+64];
            float h2a = hL[s2_*HP+lane], h2b = hL[s2_*HP+lane+64];
            float h3a = hL[s3_*HP+lane], h3b = hL[s3_*HP+lane+64];
            a0 += h0a*n0; a1 += h0b*n0; c0 += h1a*n1; c1 += h1b*n1;
            a0 += h2a*n2; a1 += h2b*n2; c0 += h3a*n3; c1 += h3b*n3;
        }
        for (; i < pe; ++i) {
            int s_ = srcl[i]; float nm = wnl[i];
            a0 += hL[s_*HP+lane]*nm; a1 += hL[s_*HP+lane+64]*nm;
        }
        a0 += c0; a1 += c1;
        p0 += fmaxf(a0 + b2v0, 0.0f);
        p1 += fmaxf(a1 + b2v1, 0.0f);
    }
    wsum[w * 128 + lane]      = p0;
    wsum[w * 128 + lane + 64] = p1;
    __syncthreads();
    if (t < Nz) {
        float s = 0.0f;
        #pragma unroll
        for (int ww = 0; ww < 16; ++ww) s += wsum[ww * 128 + t];
        inL[Hz + t] = s * (1.0f / Nz);               // pooled -> head input
    }
    __syncthreads();

    // ---- headB: pooled @ Wf1[768:896] (all threads, 16 k each) ----
    float* redB  = (float*)Bs;                       // [8][256]
    float* hvecL = ((float*)Bs) + 2048;              // [256]
    {
        int f2 = t & 127, kc8 = t >> 7;
        const float* Wp = Wf1 + (size_t)(Hz + kc8 * 16) * FHz + f2 * 2;
        const float* ip = inL + Hz + kc8 * 16;
        float ax = 0.f, ay = 0.f;
        #pragma unroll
        for (int k = 0; k < 16; ++k) {
            float iv = ip[k];
            float2 wv = *(const float2*)&Wp[(size_t)k * FHz];
            ax += iv * wv.x; ay += iv * wv.y;
        }
        redB[kc8 * 256 + f2 * 2]     = ax;
        redB[kc8 * 256 + f2 * 2 + 1] = ay;
    }
    __syncthreads();
    if (t < 128) {
        float sx = bf1[2 * t], sy = bf1[2 * t + 1];
        #pragma unroll
        for (int m = 0; m < 4; ++m) { sx += redA[m * 256 + 2 * t]; sy += redA[m * 256 + 2 * t + 1]; }
        #pragma unroll
        for (int m = 0; m < 8; ++m) { sx += redB[m * 256 + 2 * t]; sy += redB[m * 256 + 2 * t + 1]; }
        hvecL[2 * t]     = fmaxf(sx, 0.0f);
        hvecL[2 * t + 1] = fmaxf(sy, 0.0f);
    }
    __syncthreads();
    if (t < 128) {
        int l = t >> 6, j0 = t & 63;
        float s = 0.0f;
        #pragma unroll
        for (int m = 0; m < 4; ++m) s += hvecL[j0 + 64 * m] * Wf2[(j0 + 64 * m) * Lz + l];
        #pragma unroll
        for (int o = 32; o > 0; o >>= 1) s += __shfl_down(s, o);
        if (j0 == 0) outG[b * Lz + l] = s + bf2[l];
    }
}

extern "C" void kernel_launch(void* const* d_in, const int* in_sizes, int n_in,
                              void* d_out, int out_size, void* d_ws, size_t ws_size,
                              hipStream_t stream) {
    const float* lh     = (const float*)d_in[0];
    const int*   submap = (const int*)d_in[1];
    const int*   ei     = (const int*)d_in[2];
    const float* wr  = (const float*)d_in[4];
    const float* br  = (const float*)d_in[5];
    const float* W1  = (const float*)d_in[6];
    const float* b1  = (const float*)d_in[7];
    const float* W2  = (const float*)d_in[8];
    const float* b2  = (const float*)d_in[9];
    const float* Wf1 = (const float*)d_in[10];
    const float* bf1 = (const float*)d_in[11];
    const float* Wf2 = (const float*)d_in[12];
    const float* bf2 = (const float*)d_in[13];
    float* out = (float*)d_out;

    // ---- workspace layout (16B-aligned chunks) ----
    char* p = (char*)d_ws;
    ushort* nfb  = (ushort*)p;  p += (size_t)BNz * Hz * 2;      // 12.6 MB bf16
    ushort* W1T  = (ushort*)p;  p += (size_t)Hz * GHz * 2;      // transposed [n][k]
    ushort* W2T  = (ushort*)p;  p += (size_t)GHz * GHz * 2;     // transposed [n][k]
    int*    rowptrG = (int*)p;  p += (size_t)Bz * (Nz + 1) * 4;
    int*    srcsG   = (int*)p;  p += (size_t)Bz * Ez * 4;
    float*  wnG     = (float*)p; p += (size_t)Bz * Ez * 4;
    float*  dinvG   = (float*)p; p += (size_t)Bz * Nz * 4;

    // 2 dispatches; no memsets, no global atomics; GNN+head intermediates never leave LDS
    k_stage<<<8192 + 384 + 64, 256, 0, stream>>>(lh, submap, wr, br, W1, W2, ei,
                                                 nfb, W1T, W2T, rowptrG, srcsG, wnG, dinvG);
    k_gnn_fused<<<Bz, 1024, 0, stream>>>(nfb, W1T, W2T, rowptrG, srcsG, wnG, dinvG,
                                         b1, b2, lh, Wf1, bf1, Wf2, bf2, out);
}

// Round 7
// 202.415 us; speedup vs baseline: 1.2034x; 1.0249x over previous
//
#include <hip/hip_runtime.h>
#include <math.h>

#define Bz 64
#define Sz 512
#define Hz 768
#define Nz 128
#define Ez 1024
#define GHz 128
#define FHz 256
#define Lz 2
#define BNz (Bz * Nz)          // 8192

typedef short bf16x8 __attribute__((ext_vector_type(8)));
typedef float f32x4  __attribute__((ext_vector_type(4)));
typedef unsigned short ushort;

__device__ inline ushort f2b(float f) {          // f32 -> bf16 bits, round-to-nearest-even
    union { float f; unsigned u; } v; v.f = f;
    return (ushort)((v.u + 0x7FFFu + ((v.u >> 16) & 1u)) >> 16);
}

// ============ k_stage =========================================================================
// blk 0..63     : headA  -- cls @ Wf1[0:768] -> redA_G[b][256]  (moved out of gnn; overlaps gather)
// blk 64..75    : W1 transpose, LDS-staged 64x128 tiles (coalesced writes; old version scattered 2B)
// blk 76..77    : W2 transpose
// blk 78..141   : CSR build (1/batch)
// blk 142..8333 : node gather (256 thr, 4 waves)
__global__ __launch_bounds__(256) void k_stage(
        const float* __restrict__ lh, const int* __restrict__ submap,
        const float* __restrict__ wr, const float* __restrict__ br,
        const float* __restrict__ W1, const float* __restrict__ W2,
        const int* __restrict__ ei, const float* __restrict__ Wf1,
        ushort* __restrict__ nfb, ushort* __restrict__ W1T, ushort* __restrict__ W2T,
        int* __restrict__ rowptrG, int* __restrict__ srcsG,
        float* __restrict__ wnG, float* __restrict__ dinvG,
        float* __restrict__ redA_G) {
    int blk = blockIdx.x, t = threadIdx.x;       // 256 threads
    __shared__ __align__(16) char arena[17408];

    if (blk < 64) {                              // ---- headA ----
        int b = blk;
        float* clsL = (float*)arena;             // 3072
        float* pA   = (float*)(arena + 3072);    // 2048
        clsL[t]       = lh[(size_t)b * Sz * Hz + t];
        clsL[t + 256] = lh[(size_t)b * Sz * Hz + t + 256];
        clsL[t + 512] = lh[(size_t)b * Sz * Hz + t + 512];
        __syncthreads();
        int f2 = t & 127, kc = t >> 7;           // 2-way k split, 384 each
        const float* Wp = Wf1 + (size_t)(kc * 384) * FHz + f2 * 2;
        const float* ip = clsL + kc * 384;
        float ax = 0.f, ay = 0.f;
        #pragma unroll 8
        for (int k = 0; k < 384; ++k) {
            float iv = ip[k];
            float2 wv = *(const float2*)&Wp[(size_t)k * FHz];
            ax += iv * wv.x; ay += iv * wv.y;
        }
        pA[kc * 256 + f2 * 2]     = ax;
        pA[kc * 256 + f2 * 2 + 1] = ay;
        __syncthreads();
        if (t < 128) {
            float2 o;
            o.x = pA[2 * t]     + pA[256 + 2 * t];
            o.y = pA[2 * t + 1] + pA[256 + 2 * t + 1];
            *(float2*)&redA_G[b * 256 + 2 * t] = o;
        }
        return;
    }
    if (blk < 78) {                              // ---- weight transpose, 64x128 LDS tiles ----
        ushort* sT = (ushort*)arena;             // [64][136] = 17408B
        bool isW2 = (blk >= 76);
        int T = isW2 ? (blk - 76) : (blk - 64);
        int k0 = T * 64;
        const float* Wsrc = isW2 ? W2 : W1;
        #pragma unroll
        for (int j = 0; j < 32; ++j) {
            int idx = j * 256 + t;               // 8192 = 64k x 128n
            int k = idx >> 7, n = idx & 127;
            sT[k * 136 + n] = f2b(Wsrc[(size_t)(k0 + k) * 128 + n]);
        }
        __syncthreads();
        if (isW2) {
            #pragma unroll
            for (int j = 0; j < 32; ++j) {
                int idx = j * 256 + t;
                int n = idx >> 6, k = idx & 63;
                W2T[n * GHz + k0 + k] = sT[k * 136 + n];
            }
        } else {
            #pragma unroll
            for (int j = 0; j < 32; ++j) {
                int idx = j * 256 + t;
                int n = idx >> 6, k = idx & 63;
                W1T[n * Hz + k0 + k] = sT[k * 136 + n];
            }
        }
        return;
    }
    if (blk < 142) {                             // ---- CSR build, 1 block per batch ----
        int b = blk - 78;
        int*   srcl2 = (int*)arena;              // 4096
        int*   dstl2 = (int*)(arena + 4096);     // 4096
        int*   hist  = (int*)(arena + 8192);     // 512
        int*   off   = (int*)(arena + 8704);     // 512
        int*   rp    = (int*)(arena + 9216);     // 516
        float* di    = (float*)(arena + 9732);   // 512
        if (t < Nz) { hist[t] = 0; off[t] = 0; }
        __syncthreads();
        #pragma unroll
        for (int j = 0; j < 4; ++j) {
            int e = t + 256 * j;
            int s = ei[b * 2 * Ez + e], d = ei[b * 2 * Ez + Ez + e];
            srcl2[e] = s; dstl2[e] = d;
            atomicAdd(&hist[d], 1);
        }
        __syncthreads();
        if (t < Nz) {
            di[t] = rsqrtf((float)hist[t] + 1.0f);
            dinvG[b * Nz + t] = di[t];
        }
        __syncthreads();
        if (t < 64) {                            // wave shuffle-scan over 128 buckets
            int s0 = hist[2 * t], s1 = hist[2 * t + 1];
            int tot = s0 + s1, run = tot;
            #pragma unroll
            for (int o = 1; o < 64; o <<= 1) {
                int v = __shfl_up(run, o);
                if (t >= o) run += v;
            }
            int excl = run - tot;
            rp[2 * t] = excl; rp[2 * t + 1] = excl + s0;
            if (t == 63) rp[Nz] = run;
        }
        __syncthreads();
        #pragma unroll
        for (int j = 0; j < 4; ++j) {
            int e = t + 256 * j;
            int s = srcl2[e], d = dstl2[e];
            int pos = rp[d] + atomicAdd(&off[d], 1);
            srcsG[b * Ez + pos] = s;
            wnG[b * Ez + pos] = di[s] * di[d];
        }
        if (t < Nz) rowptrG[b * (Nz + 1) + t] = rp[t];
        if (t == 0) rowptrG[b * (Nz + 1) + Nz] = rp[Nz];
        return;
    }

    // ---- node gather: block = (b,n); 4 waves split rows; wave-synchronous gate ----
    int g = blk - 142;
    int b = g >> 7, n = g & 127;
    int lane = t & 63, wid = t >> 6;             // 4 waves
    float* partial = (float*)arena;              // 9216 (waves 1..3)
    int*   list    = (int*)(arena + 9216);       // 2048
    int*   lcnt    = (int*)(arena + 11264);
    if (t == 0) *lcnt = 0;
    __syncthreads();
    #pragma unroll
    for (int j = 0; j < 2; ++j) {
        int s = t + 256 * j;
        if (submap[b * Sz + s] == n) { int p = atomicAdd(lcnt, 1); list[p] = s; }
    }
    __syncthreads();
    int cnt = *lcnt;
    float brv = br[0];
    const float* wp = wr + lane * 12;
    float4 w0 = *(const float4*)&wp[0];
    float4 w1 = *(const float4*)&wp[4];
    float4 w2 = *(const float4*)&wp[8];
    float4 a0 = {0,0,0,0}, a1 = {0,0,0,0}, a2 = {0,0,0,0};
    for (int i = wid; i < cnt; i += 4) {
        const float* x = lh + (size_t)(b * Sz + list[i]) * Hz + lane * 12;
        float4 v0 = *(const float4*)&x[0];
        float4 v1 = *(const float4*)&x[4];
        float4 v2 = *(const float4*)&x[8];
        float p = v0.x*w0.x + v0.y*w0.y + v0.z*w0.z + v0.w*w0.w
                + v1.x*w1.x + v1.y*w1.y + v1.z*w1.z + v1.w*w1.w
                + v2.x*w2.x + v2.y*w2.y + v2.z*w2.z + v2.w*w2.w;
        #pragma unroll
        for (int o = 32; o > 0; o >>= 1) p += __shfl_down(p, o);
        float z = __shfl(p, 0) + brv;
        float g2 = 1.0f / (1.0f + __expf(-z));
        a0.x += g2*v0.x; a0.y += g2*v0.y; a0.z += g2*v0.z; a0.w += g2*v0.w;
        a1.x += g2*v1.x; a1.y += g2*v1.y; a1.z += g2*v1.z; a1.w += g2*v1.w;
        a2.x += g2*v2.x; a2.y += g2*v2.y; a2.z += g2*v2.z; a2.w += g2*v2.w;
    }
    if (wid > 0) {
        float* pp = partial + (wid - 1) * Hz + lane * 12;
        *(float4*)&pp[0] = a0; *(float4*)&pp[4] = a1; *(float4*)&pp[8] = a2;
    }
    __syncthreads();
    if (wid == 0) {
        float invc = 1.0f / fmaxf((float)cnt, 1.0f);
        #pragma unroll
        for (int m = 0; m < 3; ++m) {
            const float* pp = partial + m * Hz + lane * 12;
            float4 p0 = *(const float4*)&pp[0];
            float4 p1 = *(const float4*)&pp[4];
            float4 p2 = *(const float4*)&pp[8];
            a0.x += p0.x; a0.y += p0.y; a0.z += p0.z; a0.w += p0.w;
            a1.x += p1.x; a1.y += p1.y; a1.z += p1.z; a1.w += p1.w;
            a2.x += p2.x; a2.y += p2.y; a2.z += p2.z; a2.w += p2.w;
        }
        float o[12];
        o[0]=a0.x*invc; o[1]=a0.y*invc; o[2]=a0.z*invc;  o[3]=a0.w*invc;
        o[4]=a1.x*invc; o[5]=a1.y*invc; o[6]=a1.z*invc;  o[7]=a1.w*invc;
        o[8]=a2.x*invc; o[9]=a2.y*invc; o[10]=a2.z*invc; o[11]=a2.w*invc;
        unsigned* ob = (unsigned*)(nfb + (size_t)(b * Nz + n) * Hz + lane * 12);
        #pragma unroll
        for (int j = 0; j < 6; ++j)
            ob[j] = (unsigned)f2b(o[2*j]) | ((unsigned)f2b(o[2*j+1]) << 16);
    }
}

// ============ fused per-batch GNN + head tail, 1024 threads = 16 waves (4x4 wave grid) ========
// vs round 6: (1) GEMM1 2-deep ping-pong prefetch (ds_write operands land 2 phases early ->
// ~zero vmcnt drain at barriers); (2) GEMM2 via T14: W2T->regs issued BEFORE edge1, LDS write
// into the dead As+Bs region after it, 4 barrier-free K-steps, zero global stalls; (3) edge
// phases on all 16 waves with hL as paired float2 (1 ds_read_b64/edge, was 2 b32);
// (4) headA moved to k_stage (redA via global). One LDS arena with explicit unions.
#define GSP 72                  // GEMM1 staging row stride in bf16 (144B = 9x16)
#define O_BS    18432
#define O_HL    36864           // hL float2[128][64] = 65536
#define O_XB    102400          // xb [128][136] ushort = 34816 ; wsum/redB overlay post-GEMM2
#define O_RP    137216
#define O_SRC   137744
#define O_WN    141840
#define O_DIL   145936
#define O_POOL  146448
#define O_HVEC  146960          // total 147984
__global__ __launch_bounds__(1024) void k_gnn_fused(
        const ushort* __restrict__ nfb, const ushort* __restrict__ W1T,
        const ushort* __restrict__ W2T,
        const int* __restrict__ rowptrG, const int* __restrict__ srcsG,
        const float* __restrict__ wnG, const float* __restrict__ dinvG,
        const float* __restrict__ b1, const float* __restrict__ b2,
        const float* __restrict__ redA_G,
        const float* __restrict__ Wf1, const float* __restrict__ bf1,
        const float* __restrict__ Wf2, const float* __restrict__ bf2,
        float* __restrict__ outG) {
    __shared__ __align__(16) char Lar[147984];
    ushort* As   = (ushort*)(Lar);               // GEMM1 A staging; dead after GEMM1
    ushort* Bs   = (ushort*)(Lar + O_BS);        // GEMM1 B staging; dead after GEMM1
    ushort* W2s  = (ushort*)(Lar);               // [128][136] overlays As+Bs post-GEMM1
    float*  hLf  = (float*)(Lar + O_HL);         // [128][128]: row*128 + (col&63)*2 + (col>>6)
    ushort* xb   = (ushort*)(Lar + O_XB);        // x1 bf16 [128][136]
    float*  wsum = (float*)(Lar + O_XB);         // [16][128] overlays xb post-GEMM2
    float*  redB = (float*)(Lar + O_XB + 8192);  // [8][256]
    int*    rp   = (int*)(Lar + O_RP);
    int*    srcl = (int*)(Lar + O_SRC);
    float*  wnl  = (float*)(Lar + O_WN);
    float*  dil  = (float*)(Lar + O_DIL);
    float*  pooledL = (float*)(Lar + O_POOL);
    float*  hvecL   = (float*)(Lar + O_HVEC);
    const float2* hL2 = (const float2*)hLf;

    int b = blockIdx.x;
    int t = threadIdx.x;
    int w = t >> 6, lane = t & 63;
    int q = lane >> 4, l16 = lane & 15;
    int wm = w >> 2, wn2 = w & 3;                // wave tile: rows wm*32+, cols wn2*32+
    int kq = q * 8;
    int ar = t >> 3, as_ = t & 7;                // staging: 1024 uint4 chunks / tile

    // ---- GEMM1 first two tiles' loads FIRST (cold nfb miss overlaps CSR staging) ----
    const ushort* Ab = nfb + (size_t)b * Nz * Hz;
    uint4 aA, bA, aB, bB;
    aA = *(const uint4*)&Ab[(size_t)ar * Hz + 0  + as_ * 8];
    bA = *(const uint4*)&W1T[(size_t)ar * Hz + 0  + as_ * 8];
    aB = *(const uint4*)&Ab[(size_t)ar * Hz + 64 + as_ * 8];
    bB = *(const uint4*)&W1T[(size_t)ar * Hz + 64 + as_ * 8];
    __builtin_amdgcn_sched_barrier(0);

    // ---- CSR -> LDS (1 elem/thread) ----
    if (t < Nz + 1) rp[t] = rowptrG[b * (Nz + 1) + t];
    if (t < Nz) dil[t] = dinvG[b * Nz + t];
    srcl[t] = srcsG[b * Ez + t];
    wnl[t]  = wnG[b * Ez + t];

    f32x4 acc00 = {0,0,0,0}, acc01 = {0,0,0,0}, acc10 = {0,0,0,0}, acc11 = {0,0,0,0};
    auto mfma_tile = [&]() {
        #pragma unroll
        for (int ks = 0; ks < 64; ks += 32) {
            bf16x8 af0 = *(const bf16x8*)&As[(wm * 32 +      l16) * GSP + ks + kq];
            bf16x8 af1 = *(const bf16x8*)&As[(wm * 32 + 16 + l16) * GSP + ks + kq];
            bf16x8 bv0 = *(const bf16x8*)&Bs[(wn2 * 32 +      l16) * GSP + ks + kq];
            bf16x8 bv1 = *(const bf16x8*)&Bs[(wn2 * 32 + 16 + l16) * GSP + ks + kq];
            acc00 = __builtin_amdgcn_mfma_f32_16x16x32_bf16(af0, bv0, acc00, 0, 0, 0);
            acc01 = __builtin_amdgcn_mfma_f32_16x16x32_bf16(af0, bv1, acc01, 0, 0, 0);
            acc10 = __builtin_amdgcn_mfma_f32_16x16x32_bf16(af1, bv0, acc10, 0, 0, 0);
            acc11 = __builtin_amdgcn_mfma_f32_16x16x32_bf16(af1, bv1, acc11, 0, 0, 0);
        }
    };

    // ---- GEMM1: 12 tiles, 2-deep ping-pong (6 iterations, 2 tiles each) ----
    for (int k0 = 0; k0 < Hz; k0 += 128) {
        __syncthreads();
        *(uint4*)&As[ar * GSP + as_ * 8] = aA;
        *(uint4*)&Bs[ar * GSP + as_ * 8] = bA;
        if (k0 + 128 < Hz) {
            aA = *(const uint4*)&Ab[(size_t)ar * Hz + k0 + 128 + as_ * 8];
            bA = *(const uint4*)&W1T[(size_t)ar * Hz + k0 + 128 + as_ * 8];
        }
        __builtin_amdgcn_sched_barrier(0);
        __syncthreads();
        mfma_tile();
        __syncthreads();
        *(uint4*)&As[ar * GSP + as_ * 8] = aB;
        *(uint4*)&Bs[ar * GSP + as_ * 8] = bB;
        if (k0 + 192 < Hz) {
            aB = *(const uint4*)&Ab[(size_t)ar * Hz + k0 + 192 + as_ * 8];
            bB = *(const uint4*)&W1T[(size_t)ar * Hz + k0 + 192 + as_ * 8];
        }
        __builtin_amdgcn_sched_barrier(0);
        __syncthreads();
        mfma_tile();
    }
    // C-write: hLf[row*128 + (col&63)*2 + (col>>6)]  (hLf region disjoint from staging)
    {
        int c0 = wn2 * 32 + l16, c1 = c0 + 16;
        #pragma unroll
        for (int r = 0; r < 4; ++r) {
            int r0 = (wm * 32 + q * 4 + r) * 128, r1 = r0 + 16 * 128;
            hLf[r0 + (c0 & 63) * 2 + (c0 >> 6)] = acc00[r];
            hLf[r0 + (c1 & 63) * 2 + (c1 >> 6)] = acc01[r];
            hLf[r1 + (c0 & 63) * 2 + (c0 >> 6)] = acc10[r];
            hLf[r1 + (c1 & 63) * 2 + (c1 >> 6)] = acc11[r];
        }
    }
    __syncthreads();                             // hL complete; As/Bs dead

    // ---- T14: issue W2T loads now; latency hides under edge1 ----
    int n0 = t >> 4, sg = t & 15;                // chunk t      : rows 0..63
    uint4 w2r0 = *(const uint4*)&W2T[n0 * GHz + sg * 8];
    uint4 w2r1 = *(const uint4*)&W2T[(n0 + 64) * GHz + sg * 8];   // chunk t+1024
    __builtin_amdgcn_sched_barrier(0);

    // ---- edge1 (ALL 16 waves): x1 = relu(agg(hL) + b1) -> xb bf16 ----
    float bx0 = b1[lane], bx1 = b1[lane + 64];
    for (int d = w; d < Nz; d += 16) {
        float dd = dil[d];
        float2 hv = hL2[d * 64 + lane];
        float a0 = hv.x * dd * dd, a1 = hv.y * dd * dd;
        float c0 = 0.f, c1 = 0.f;
        int i = rp[d], pe = rp[d + 1];
        for (; i + 4 <= pe; i += 4) {
            int s0_ = srcl[i], s1_ = srcl[i+1], s2_ = srcl[i+2], s3_ = srcl[i+3];
            float m0 = wnl[i], m1 = wnl[i+1], m2 = wnl[i+2], m3 = wnl[i+3];
            float2 h0 = hL2[s0_ * 64 + lane], h1 = hL2[s1_ * 64 + lane];
            float2 h2 = hL2[s2_ * 64 + lane], h3 = hL2[s3_ * 64 + lane];
            a0 += h0.x*m0; a1 += h0.y*m0; c0 += h1.x*m1; c1 += h1.y*m1;
            a0 += h2.x*m2; a1 += h2.y*m2; c0 += h3.x*m3; c1 += h3.y*m3;
        }
        for (; i < pe; ++i) {
            int s_ = srcl[i]; float nm = wnl[i];
            float2 h = hL2[s_ * 64 + lane];
            a0 += h.x * nm; a1 += h.y * nm;
        }
        a0 += c0; a1 += c1;
        xb[d * 136 + lane]      = f2b(fmaxf(a0 + bx0, 0.0f));
        xb[d * 136 + lane + 64] = f2b(fmaxf(a1 + bx1, 0.0f));
    }
    __syncthreads();                             // xb complete; safe to overwrite As/Bs region

    // ---- stage W2 (full 128x128) into W2s; single phase ----
    *(uint4*)((char*)W2s + n0 * 272 + sg * 16)        = w2r0;
    *(uint4*)((char*)W2s + (n0 + 64) * 272 + sg * 16) = w2r1;
    __syncthreads();

    // ---- GEMM2: hL = x1(128x128) @ W2(128x128); 4 barrier-free K-steps ----
    acc00 = (f32x4){0,0,0,0}; acc01 = (f32x4){0,0,0,0};
    acc10 = (f32x4){0,0,0,0}; acc11 = (f32x4){0,0,0,0};
    #pragma unroll
    for (int ks = 0; ks < GHz; ks += 32) {
        bf16x8 af0 = *(const bf16x8*)&xb[(wm * 32 +      l16) * 136 + ks + kq];
        bf16x8 af1 = *(const bf16x8*)&xb[(wm * 32 + 16 + l16) * 136 + ks + kq];
        bf16x8 bv0 = *(const bf16x8*)&W2s[(wn2 * 32 +      l16) * 136 + ks + kq];
        bf16x8 bv1 = *(const bf16x8*)&W2s[(wn2 * 32 + 16 + l16) * 136 + ks + kq];
        acc00 = __builtin_amdgcn_mfma_f32_16x16x32_bf16(af0, bv0, acc00, 0, 0, 0);
        acc01 = __builtin_amdgcn_mfma_f32_16x16x32_bf16(af0, bv1, acc01, 0, 0, 0);
        acc10 = __builtin_amdgcn_mfma_f32_16x16x32_bf16(af1, bv0, acc10, 0, 0, 0);
        acc11 = __builtin_amdgcn_mfma_f32_16x16x32_bf16(af1, bv1, acc11, 0, 0, 0);
    }
    __syncthreads();                             // all edge1-era hL reads long done; GEMM2 reads of xb done below? no: this barrier is for hLf rewrite vs nothing -- hLf disjoint from xb/W2s; barrier orders hLf writes after all waves' prior hL2 reads (edge1) which ended before xb barrier. Kept for wsum overlay safety.
    {
        int c0 = wn2 * 32 + l16, c1 = c0 + 16;
        #pragma unroll
        for (int r = 0; r < 4; ++r) {
            int r0 = (wm * 32 + q * 4 + r) * 128, r1 = r0 + 16 * 128;
            hLf[r0 + (c0 & 63) * 2 + (c0 >> 6)] = acc00[r];
            hLf[r0 + (c1 & 63) * 2 + (c1 >> 6)] = acc01[r];
            hLf[r1 + (c0 & 63) * 2 + (c0 >> 6)] = acc10[r];
            hLf[r1 + (c1 & 63) * 2 + (c1 >> 6)] = acc11[r];
        }
    }
    __syncthreads();                             // hL(layer2) complete; xb dead -> wsum overlay ok

    // ---- edge2 + mean-pool (all 16 waves; x2 never materialized) ----
    float by0 = b2[lane], by1 = b2[lane + 64];
    float p0 = 0.0f, p1 = 0.0f;
    for (int d = w; d < Nz; d += 16) {
        float dd = dil[d];
        float2 hv = hL2[d * 64 + lane];
        float a0 = hv.x * dd * dd, a1 = hv.y * dd * dd;
        float c0 = 0.f, c1 = 0.f;
        int i = rp[d], pe = rp[d + 1];
        for (; i + 4 <= pe; i += 4) {
            int s0_ = srcl[i], s1_ = srcl[i+1], s2_ = srcl[i+2], s3_ = srcl[i+3];
            float m0 = wnl[i], m1 = wnl[i+1], m2 = wnl[i+2], m3 = wnl[i+3];
            float2 h0 = hL2[s0_ * 64 + lane], h1 = hL2[s1_ * 64 + lane];
            float2 h2 = hL2[s2_ * 64 + lane], h3 = hL2[s3_ * 64 + lane];
            a0 += h0.x*m0; a1 += h0.y*m0; c0 += h1.x*m1; c1 += h1.y*m1;
            a0 += h2.x*m2; a1 += h2.y*m2; c0 += h3.x*m3; c1 += h3.y*m3;
        }
        for (; i < pe; ++i) {
            int s_ = srcl[i]; float nm = wnl[i];
            float2 h = hL2[s_ * 64 + lane];
            a0 += h.x * nm; a1 += h.y * nm;
        }
        a0 += c0; a1 += c1;
        p0 += fmaxf(a0 + by0, 0.0f);
        p1 += fmaxf(a1 + by1, 0.0f);
    }
    wsum[w * 128 + lane]      = p0;
    wsum[w * 128 + lane + 64] = p1;
    __syncthreads();
    if (t < Nz) {
        float s = 0.0f;
        #pragma unroll
        for (int ww = 0; ww < 16; ++ww) s += wsum[ww * 128 + t];
        pooledL[t] = s * (1.0f / Nz);
    }
    __syncthreads();

    // ---- headB: pooled @ Wf1[768:896] (all threads, 16 k each) ----
    {
        int f2 = t & 127, kc8 = t >> 7;
        const float* Wp = Wf1 + (size_t)(Hz + kc8 * 16) * FHz + f2 * 2;
        const float* ip = pooledL + kc8 * 16;
        float ax = 0.f, ay = 0.f;
        #pragma unroll
        for (int k = 0; k < 16; ++k) {
            float iv = ip[k];
            float2 wv = *(const float2*)&Wp[(size_t)k * FHz];
            ax += iv * wv.x; ay += iv * wv.y;
        }
        redB[kc8 * 256 + f2 * 2]     = ax;
        redB[kc8 * 256 + f2 * 2 + 1] = ay;
    }
    __syncthreads();
    if (t < 128) {
        float sx = bf1[2 * t]     + redA_G[b * 256 + 2 * t];
        float sy = bf1[2 * t + 1] + redA_G[b * 256 + 2 * t + 1];
        #pragma unroll
        for (int m = 0; m < 8; ++m) { sx += redB[m * 256 + 2 * t]; sy += redB[m * 256 + 2 * t + 1]; }
        hvecL[2 * t]     = fmaxf(sx, 0.0f);
        hvecL[2 * t + 1] = fmaxf(sy, 0.0f);
    }
    __syncthreads();
    if (t < 128) {
        int l = t >> 6, j0 = t & 63;
        float s = 0.0f;
        #pragma unroll
        for (int m = 0; m < 4; ++m) s += hvecL[j0 + 64 * m] * Wf2[(j0 + 64 * m) * Lz + l];
        #pragma unroll
        for (int o = 32; o > 0; o >>= 1) s += __shfl_down(s, o);
        if (j0 == 0) outG[b * Lz + l] = s + bf2[l];
    }
}

extern "C" void kernel_launch(void* const* d_in, const int* in_sizes, int n_in,
                              void* d_out, int out_size, void* d_ws, size_t ws_size,
                              hipStream_t stream) {
    const float* lh     = (const float*)d_in[0];
    const int*   submap = (const int*)d_in[1];
    const int*   ei     = (const int*)d_in[2];
    const float* wr  = (const float*)d_in[4];
    const float* br  = (const float*)d_in[5];
    const float* W1  = (const float*)d_in[6];
    const float* b1  = (const float*)d_in[7];
    const float* W2  = (const float*)d_in[8];
    const float* b2  = (const float*)d_in[9];
    const float* Wf1 = (const float*)d_in[10];
    const float* bf1 = (const float*)d_in[11];
    const float* Wf2 = (const float*)d_in[12];
    const float* bf2 = (const float*)d_in[13];
    float* out = (float*)d_out;

    // ---- workspace layout (16B-aligned chunks) ----
    char* p = (char*)d_ws;
    ushort* nfb  = (ushort*)p;  p += (size_t)BNz * Hz * 2;      // 12.6 MB bf16
    ushort* W1T  = (ushort*)p;  p += (size_t)Hz * GHz * 2;      // transposed [n][k]
    ushort* W2T  = (ushort*)p;  p += (size_t)GHz * GHz * 2;     // transposed [n][k]
    int*    rowptrG = (int*)p;  p += (size_t)Bz * (Nz + 1) * 4;
    int*    srcsG   = (int*)p;  p += (size_t)Bz * Ez * 4;
    float*  wnG     = (float*)p; p += (size_t)Bz * Ez * 4;
    float*  dinvG   = (float*)p; p += (size_t)Bz * Nz * 4;
    float*  redA_G  = (float*)p; p += (size_t)Bz * FHz * 4;     // headA partials (final)

    // 2 dispatches; no memsets, no global atomics; GNN+head intermediates never leave LDS
    k_stage<<<142 + 8192, 256, 0, stream>>>(lh, submap, wr, br, W1, W2, ei, Wf1,
                                            nfb, W1T, W2T, rowptrG, srcsG, wnG, dinvG, redA_G);
    k_gnn_fused<<<Bz, 1024, 0, stream>>>(nfb, W1T, W2T, rowptrG, srcsG, wnG, dinvG,
                                         b1, b2, redA_G, Wf1, bf1, Wf2, bf2, out);
}